// Round 11
// baseline (431.645 us; speedup 1.0000x reference)
//
#include <hip/hip_runtime.h>

#define N_NODES 50000
#define N_EDGES 800000
#define IN_DIM 32
#define HD 256   // H*D
#define H_ 8
#define D_ 32
#define ECAP 64  // edges stashed in LDS per node (recompute tail beyond)
#define NT 17    // 16 W1 col-tiles + 1 Wa1 tile (el/er)

#define NB_ZERO ((N_NODES+255)/256)     // 196
#define NB_PACK ((8*NT*64*8+255)/256)   // 272
#define NB_PW0  32
#define NB_EL0  (N_NODES/16)            // 3125

typedef __attribute__((ext_vector_type(8))) short bf16x8;
typedef __attribute__((ext_vector_type(4))) float f32x4;
typedef __attribute__((ext_vector_type(8))) unsigned short u16x8;

__device__ inline unsigned short f2b(float f){
  union{float f;unsigned int u;}v; v.f=f;
  unsigned int r=(v.u + 0x7FFFu + ((v.u>>16)&1u))>>16;
  return (unsigned short)r;
}
__device__ inline float b2f(unsigned short u){
  union{float f;unsigned int u32;}v; v.u32=((unsigned int)u)<<16; return v.f;
}

// ---------------- fused init: deg-zero | pack W1+Wa1 | pack W0t | el0+xb ----------------

__global__ __launch_bounds__(256) void k_init(const float* __restrict__ h,
    const float* __restrict__ W0, const float* __restrict__ al0, const float* __restrict__ ar0,
    const float* __restrict__ W1, const float* __restrict__ al1, const float* __restrict__ ar1,
    int* __restrict__ deg, unsigned short* __restrict__ Wp, unsigned short* __restrict__ W0t,
    float* __restrict__ elr0, unsigned short* __restrict__ xb){
  int b = blockIdx.x;
  int tid = threadIdx.x;
  if (b < NB_ZERO){
    int i = b*256+tid;
    if (i<N_NODES) deg[i]=0;
    return;
  }
  if (b < NB_ZERO+NB_PACK){
    int t = (b-NB_ZERO)*256+tid;
    if (t < 8*NT*64*8){
      int j=t&7, lane=(t>>3)&63;
      int g=t>>9; int nt=g%NT, ks=g/NT;
      int k = ks*32 + (lane>>4)*8 + j;
      float v;
      if (nt<16){
        v = W1[(size_t)k*HD + nt*16 + (lane&15)];
      } else {
        int jj = lane&15, hh = jj&7;
        const float* av = (jj<8)? al1 : ar1;
        float sacc=0.f;
        #pragma unroll
        for (int d2=0; d2<32; d2++)
          sacc = fmaf(W1[(size_t)k*HD + hh*32 + d2], av[hh*32+d2], sacc);
        v = sacc;
      }
      Wp[t] = f2b(v);
    }
    return;
  }
  if (b < NB_ZERO+NB_PACK+NB_PW0){
    int t = (b-NB_ZERO-NB_PACK)*256+tid;
    if (t < 8192){
      int q = t&7, c = (t>>3)&255, kb = t>>11;
      W0t[t] = f2b(W0[(size_t)(kb*8+q)*HD + c]);
    }
    return;
  }
  // ---- el0 part: elr0 + xb, Wa0 computed inline ----
  int eb = b - (NB_ZERO+NB_PACK+NB_PW0);
  __shared__ float sWa[IN_DIM*16];
  __shared__ float sx[16][IN_DIM+1];
  int nb = eb*16;
  for (int e=tid; e<IN_DIM*16; e+=256){
    int k=e>>4, j=e&15, hh=j&7;
    const float* av = (j<8)? al0 : ar0;
    float sacc=0.f;
    #pragma unroll
    for (int d2=0; d2<32; d2++)
      sacc = fmaf(W0[(size_t)k*HD + hh*32 + d2], av[hh*32+d2], sacc);
    sWa[e]=sacc;
  }
  for (int i=tid; i<16*IN_DIM; i+=256){
    int r=i>>5, c=i&31;
    sx[r][c] = h[(size_t)(nb+r)*IN_DIM + c];
  }
  __syncthreads();
  int node = tid>>4, j = tid&15;
  float s = 0.f;
  #pragma unroll 8
  for (int k=0;k<IN_DIM;k++) s = fmaf(sx[node][k], sWa[k*16+j], s);
  elr0[(size_t)(nb+node)*16 + j] = s;
  for (int i=tid; i<16*IN_DIM; i+=256){
    int r=i>>5, c=i&31;
    xb[(size_t)(nb+r)*IN_DIM + c] = f2b(sx[r][c]);
  }
}

// ---------------- CSR build ----------------

__global__ void k_hist(const int* __restrict__ dst, int* __restrict__ deg){
  int e = blockIdx.x*256+threadIdx.x;
  if (e < N_EDGES) atomicAdd(&deg[dst[e]], 1);
}

#define SCH 49  // ceil(50000/1024)
__global__ __launch_bounds__(1024) void k_scan(const int* __restrict__ deg,
    int* __restrict__ offs, int* __restrict__ cursor){
  __shared__ int wsum[16];
  __shared__ int total_sh;
  int tid = threadIdx.x;
  int base = tid*SCH;
  int cnt = (base < N_NODES) ? ((N_NODES-base) < SCH ? (N_NODES-base) : SCH) : 0;
  int dloc[SCH];
  int s=0;
  for (int j2=0;j2<cnt;j2++){ dloc[j2]=deg[base+j2]; s += dloc[j2]; }
  int lane = tid&63, wid = tid>>6;
  int incl = s;
  #pragma unroll
  for (int o=1;o<64;o<<=1){ int t=__shfl_up(incl,o,64); if (lane>=o) incl+=t; }
  if (lane==63) wsum[wid]=incl;
  __syncthreads();
  if (wid==0 && lane<16){
    int v = wsum[lane];
    int iv = v;
    #pragma unroll
    for (int o=1;o<16;o<<=1){ int t=__shfl_up(iv,o,64); if (lane>=o) iv+=t; }
    wsum[lane] = iv - v;               // exclusive wave base
    if (lane==15) total_sh = iv;
  }
  __syncthreads();
  int run = incl - s + wsum[wid];
  for (int j2=0;j2<cnt;j2++){
    offs[base+j2]=run; cursor[base+j2]=run; run += dloc[j2];
  }
  if (tid==0) offs[N_NODES]=total_sh;
}

__global__ void k_scatter(const int* __restrict__ src, const int* __restrict__ dst,
                          int* __restrict__ cursor, int* __restrict__ csr_src,
                          int* __restrict__ csr_eid){
  int e = blockIdx.x*256+threadIdx.x;
  if (e<N_EDGES){
    int d = dst[e];
    int pos = atomicAdd(&cursor[d],1);
    csr_src[pos]=src[e];
    csr_eid[pos]=e;
  }
}

// ---------------- FUSED layer-0 (bf16 x gather) ----------------

__global__ __launch_bounds__(256) void k_agg0f(const int* __restrict__ offs, const int* __restrict__ csr_src,
    const unsigned short* __restrict__ xb, const float* __restrict__ elr,
    const unsigned short* __restrict__ W0t, const float* __restrict__ b0,
    unsigned short* __restrict__ h1b){
  __shared__ float s_al[4][ECAP][H_];
  __shared__ int   s_sn[4][ECAP];
  __shared__ float s_m[4][H_], s_is[4][H_];
  __shared__ float s_hg[4][32*9];      // transposed hagg, stride 9 (bank-spread)
  int w = threadIdx.x>>6, lane = threadIdx.x&63;
  int n = blockIdx.x*4 + w;
  int h = lane>>3, sub = lane&7;
  int off = offs[n], deg = offs[n+1]-off;
  float er_n = elr[n*16 + 8 + h];

  // ---- phase A: scores -> LDS, online (m,s) ----
  float m=-1e30f, s=0.f;
  for (int i=sub; i<deg; i+=8){
    int sn = csr_src[off+i];
    float sc = elr[sn*16+h] + er_n;
    sc = sc>0.f? sc : 0.2f*sc;
    if (i<ECAP){ s_al[w][i][h] = sc; if (h==0) s_sn[w][i] = sn; }
    float mn = fmaxf(m,sc);
    s = s*__expf(m-mn) + __expf(sc-mn);
    m = mn;
  }
  #pragma unroll
  for (int o=4;o>=1;o>>=1){
    float m2=__shfl_xor(m,o,64), s2=__shfl_xor(s,o,64);
    float mn=fmaxf(m,m2);
    s = s*__expf(m-mn)+s2*__expf(m2-mn); m=mn;
  }
  float inv_s = (s>0.f)?1.f/s:0.f;
  if (sub==0){ s_m[w][h]=m; s_is[w][h]=inv_s; }
  int dcap = deg<ECAP? deg:ECAP;
  int dcap_pad = (dcap+15)&~15;
  for (int i=sub; i<dcap; i+=8)
    s_al[w][i][h] = __expf(s_al[w][i][h]-m)*inv_s;
  for (int i=dcap+lane; i<dcap_pad; i+=64){   // pad to 16-boundary: zero-alpha dummy edges
    s_sn[w][i]=0;
    *(float4*)&s_al[w][i][0]=make_float4(0,0,0,0);
    *(float4*)&s_al[w][i][4]=make_float4(0,0,0,0);
  }
  __syncthreads();

  // ---- phase B: tail-free 16-edge chunks, bf16 x ----
  int hw = lane>>5, d = lane&31;
  float acc[H_]  = {0,0,0,0,0,0,0,0};
  int i = hw;
  for (; i<dcap_pad; i+=16){
    float xv[8];
    #pragma unroll
    for (int q=0;q<8;q++)
      xv[q] = b2f(xb[(size_t)s_sn[w][i+2*q]*IN_DIM + d]);
    #pragma unroll
    for (int q=0;q<8;q++){
      float4 a0 = *(const float4*)&s_al[w][i+2*q][0];
      float4 a1 = *(const float4*)&s_al[w][i+2*q][4];
      acc[0]=fmaf(a0.x,xv[q],acc[0]); acc[1]=fmaf(a0.y,xv[q],acc[1]);
      acc[2]=fmaf(a0.z,xv[q],acc[2]); acc[3]=fmaf(a0.w,xv[q],acc[3]);
      acc[4]=fmaf(a1.x,xv[q],acc[4]); acc[5]=fmaf(a1.y,xv[q],acc[5]);
      acc[6]=fmaf(a1.z,xv[q],acc[6]); acc[7]=fmaf(a1.w,xv[q],acc[7]);
    }
  }
  for (; i<deg; i+=2){                    // rare tail: deg > ECAP, recompute
    int sn = csr_src[off+i];
    float xv = b2f(xb[(size_t)sn*IN_DIM + d]);
    #pragma unroll
    for (int hh=0;hh<H_;hh++){
      float sc = elr[sn*16+hh] + elr[n*16+8+hh];
      sc = sc>0.f? sc : 0.2f*sc;
      float a = __expf(sc - s_m[w][hh]) * s_is[w][hh];
      acc[hh]=fmaf(a,xv,acc[hh]);
    }
  }
  #pragma unroll
  for (int hh=0;hh<H_;hh++)
    acc[hh] += __shfl_xor(acc[hh],32,64);
  if (hw==0){
    #pragma unroll
    for (int hh=0;hh<H_;hh++) s_hg[w][d*9+hh] = acc[hh];
  }
  __syncthreads();

  // ---- epilogue (column-split): wave w computes cols [w*64, w*64+64) for ALL 4 nodes ----
  int col = w*64 + lane;
  int hcol = col>>5;
  float a0=0.f, a1=0.f, a2=0.f, a3=0.f;
  #pragma unroll
  for (int kb=0;kb<4;kb++){
    u16x8 wv8 = *(const u16x8*)(W0t + ((size_t)(kb*HD + col)<<3));
    #pragma unroll
    for (int q=0;q<8;q++){
      float wv = b2f(wv8[q]);
      int k = kb*8+q;
      a0 = fmaf(s_hg[0][k*9+hcol], wv, a0);
      a1 = fmaf(s_hg[1][k*9+hcol], wv, a1);
      a2 = fmaf(s_hg[2][k*9+hcol], wv, a2);
      a3 = fmaf(s_hg[3][k*9+hcol], wv, a3);
    }
  }
  float bb = b0[col];
  int n0 = blockIdx.x*4;
  h1b[(size_t)(n0+0)*HD+col] = f2b(fmaxf(a0+bb,0.f));
  h1b[(size_t)(n0+1)*HD+col] = f2b(fmaxf(a1+bb,0.f));
  h1b[(size_t)(n0+2)*HD+col] = f2b(fmaxf(a2+bb,0.f));
  h1b[(size_t)(n0+3)*HD+col] = f2b(fmaxf(a3+bb,0.f));
}

// ---------------- feat1 = h1b @ [W1 | Wa1] via MFMA; 32 rows/wave ----------------

__global__ __launch_bounds__(256) void k_gemm1_mfma(const unsigned short* __restrict__ h1b,
    const unsigned short* __restrict__ Wp, unsigned short* __restrict__ featb,
    float* __restrict__ elr1){
  int wv = threadIdx.x>>6, lane = threadIdx.x&63;
  int rb = blockIdx.x*128 + wv*32;
  int ar0 = rb + (lane&15);
  int ar1 = ar0 + 16;
  if (ar0 >= N_NODES) ar0 = N_NODES-1;   // clamp reads; writes guarded below
  if (ar1 >= N_NODES) ar1 = N_NODES-1;
  int kgrp = lane>>4;
  f32x4 acc0[NT], acc1[NT];
  #pragma unroll
  for (int nt=0;nt<NT;nt++){ acc0[nt]=(f32x4){0.f,0.f,0.f,0.f}; acc1[nt]=(f32x4){0.f,0.f,0.f,0.f}; }
  const unsigned short* ap0 = h1b + (size_t)ar0*HD + kgrp*8;
  const unsigned short* ap1 = h1b + (size_t)ar1*HD + kgrp*8;
  #pragma unroll
  for (int ks=0; ks<8; ks++){
    bf16x8 a0 = *(const bf16x8*)(ap0 + ks*32);
    bf16x8 a1 = *(const bf16x8*)(ap1 + ks*32);
    #pragma unroll
    for (int nt=0; nt<NT; nt++){
      bf16x8 b = *(const bf16x8*)(Wp + (((ks*NT+nt)*64+lane)<<3));
      acc0[nt] = __builtin_amdgcn_mfma_f32_16x16x32_bf16(a0, b, acc0[nt], 0, 0, 0);
      acc1[nt] = __builtin_amdgcn_mfma_f32_16x16x32_bf16(a1, b, acc1[nt], 0, 0, 0);
    }
  }
  int col = lane&15;
  int rb0 = rb + (lane>>4)*4;
  int rb1 = rb0 + 16;
  #pragma unroll
  for (int nt=0;nt<16;nt++){
    #pragma unroll
    for (int r=0;r<4;r++){
      int row0 = rb0+r, row1 = rb1+r;
      if (row0<N_NODES) featb[(size_t)row0*HD + nt*16+col] = f2b(acc0[nt][r]);
      if (row1<N_NODES) featb[(size_t)row1*HD + nt*16+col] = f2b(acc1[nt][r]);
    }
  }
  #pragma unroll
  for (int r=0;r<4;r++){
    int row0 = rb0+r, row1 = rb1+r;
    if (row0<N_NODES) elr1[(size_t)row0*16 + col] = acc0[16][r];
    if (row1<N_NODES) elr1[(size_t)row1*16 + col] = acc1[16][r];
  }
}

// ---------------- layer-1 edge softmax + aggregate + head-mean (R9 form) ----------------
// phase A: (h=lane>>3, sub=lane&7). phase B: FULL WAVE per edge, lane -> cols lane*4..+3, head lane>>3.

__global__ __launch_bounds__(256) void k_agg1(const int* __restrict__ offs, const int* __restrict__ csr_src,
   const int* __restrict__ csr_eid, const unsigned short* __restrict__ featb, const float* __restrict__ elr,
   const float* __restrict__ bias, float* __restrict__ out, float* __restrict__ alpha_out){
  __shared__ float s_al[4][ECAP][H_];
  __shared__ int   s_sn[4][ECAP];
  __shared__ int   s_eid[4][ECAP];
  int w = threadIdx.x>>6, lane = threadIdx.x&63;
  int n = blockIdx.x*4 + w;
  int h = lane>>3, sub = lane&7;
  int off = offs[n], deg = offs[n+1]-off;
  float er_n = elr[n*16 + 8 + h];

  float m=-1e30f, s=0.f;
  for (int i=sub; i<deg; i+=8){
    int p = off+i;
    int sn = csr_src[p];
    float sc = elr[sn*16+h] + er_n;
    sc = sc>0.f? sc : 0.2f*sc;
    if (i<ECAP){
      s_al[w][i][h]=sc;
      if (h==0){ s_sn[w][i]=sn; s_eid[w][i]=csr_eid[p]; }
    }
    float mn = fmaxf(m,sc);
    s = s*__expf(m-mn) + __expf(sc-mn);
    m = mn;
  }
  #pragma unroll
  for (int o=4;o>=1;o>>=1){
    float m2=__shfl_xor(m,o,64), s2=__shfl_xor(s,o,64);
    float mn=fmaxf(m,m2);
    s = s*__expf(m-mn) + s2*__expf(m2-mn);
    m = mn;
  }
  float inv_s = (s>0.f)? 1.f/s : 0.f;
  int dcap = deg<ECAP? deg:ECAP;
  int dcap_pad = (dcap+7)&~7;
  __syncthreads();   // s_eid ready before conversion pass writes alpha
  for (int i=sub; i<dcap; i+=8){
    float a = __expf(s_al[w][i][h]-m)*inv_s;
    s_al[w][i][h] = a;
    alpha_out[(size_t)s_eid[w][i]*H_ + h] = a;
  }
  for (int i=dcap+lane; i<dcap_pad; i+=64){   // pad to 8-boundary: zero-alpha dummy edges
    s_sn[w][i]=0;
    *(float4*)&s_al[w][i][0]=make_float4(0,0,0,0);
    *(float4*)&s_al[w][i][4]=make_float4(0,0,0,0);
  }
  __syncthreads();

  // ---- phase B: full-wave per edge, 8 gathers in flight ----
  int c0 = lane*4;             // cols c0..c0+3 (head h == lane>>3)
  float acc[4] = {0,0,0,0};
  for (int i=0; i<dcap_pad; i+=8){
    float av[8]; ushort4 uu[8];
    #pragma unroll
    for (int q=0;q<8;q++){
      int sn = s_sn[w][i+q];
      av[q] = s_al[w][i+q][h];
      uu[q] = *(const ushort4*)&featb[(size_t)sn*HD + c0];
    }
    #pragma unroll
    for (int q=0;q<8;q++){
      acc[0]=fmaf(av[q],b2f(uu[q].x),acc[0]);
      acc[1]=fmaf(av[q],b2f(uu[q].y),acc[1]);
      acc[2]=fmaf(av[q],b2f(uu[q].z),acc[2]);
      acc[3]=fmaf(av[q],b2f(uu[q].w),acc[3]);
    }
  }
  for (int i=ECAP; i<deg; ++i){           // rare tail: deg > ECAP, full wave per edge
    int p = off+i;
    int sn = csr_src[p];
    float sc = elr[sn*16+h] + er_n;
    sc = sc>0.f? sc : 0.2f*sc;
    float a=__expf(sc-m)*inv_s;
    ushort4 u=*(const ushort4*)&featb[(size_t)sn*HD+c0];
    acc[0]=fmaf(a,b2f(u.x),acc[0]);
    acc[1]=fmaf(a,b2f(u.y),acc[1]);
    acc[2]=fmaf(a,b2f(u.z),acc[2]);
    acc[3]=fmaf(a,b2f(u.w),acc[3]);
    if (sub==0) alpha_out[(size_t)csr_eid[p]*H_+h]=a;
  }

  // bias, then mean over heads (sum lanes with same lane&7)
  #pragma unroll
  for (int q=0;q<4;q++) acc[q] += bias[c0+q];
  #pragma unroll
  for (int o=8;o<64;o<<=1){
    #pragma unroll
    for (int q=0;q<4;q++) acc[q]+=__shfl_xor(acc[q],o,64);
  }
  if (h==0){
    float4 o0 = make_float4(acc[0]*0.125f, acc[1]*0.125f, acc[2]*0.125f, acc[3]*0.125f);
    *(float4*)&out[(size_t)n*D_ + c0] = o0;
  }
}

// ---------------- launcher ----------------

extern "C" void kernel_launch(void* const* d_in, const int* in_sizes, int n_in,
                              void* d_out, int out_size, void* d_ws, size_t ws_size,
                              hipStream_t stream){
  const float* h   = (const float*)d_in[0];
  const int*   src = (const int*)d_in[1];
  const int*   dst = (const int*)d_in[2];
  const float* W0  = (const float*)d_in[3];
  const float* al0 = (const float*)d_in[4];
  const float* ar0 = (const float*)d_in[5];
  const float* b0  = (const float*)d_in[6];
  const float* W1  = (const float*)d_in[7];
  const float* al1 = (const float*)d_in[8];
  const float* ar1 = (const float*)d_in[9];
  const float* b1  = (const float*)d_in[10];
  float* out_final = (float*)d_out;
  float* alpha_out = (float*)d_out + (size_t)N_NODES*D_;

  char* wsp = (char*)d_ws;
  auto alloc=[&](size_t bytes)->char*{ char* p=wsp; wsp += (bytes+255)&~size_t(255); return p; };
  int*   deg     = (int*)alloc((size_t)N_NODES*4);
  int*   offs    = (int*)alloc((size_t)(N_NODES+1)*4);
  int*   cursor  = (int*)alloc((size_t)N_NODES*4);
  int*   csr_src = (int*)alloc((size_t)N_EDGES*4);
  int*   csr_eid = (int*)alloc((size_t)N_EDGES*4);
  unsigned short* featb = (unsigned short*)alloc((size_t)N_NODES*HD*2);
  unsigned short* h1b   = (unsigned short*)alloc((size_t)N_NODES*HD*2);
  unsigned short* xb    = (unsigned short*)alloc((size_t)N_NODES*IN_DIM*2);
  float* elr0    = (float*)alloc((size_t)N_NODES*16*4);
  float* elr1    = (float*)alloc((size_t)N_NODES*16*4);
  unsigned short* Wp  = (unsigned short*)alloc((size_t)8*NT*64*8*2);
  unsigned short* W0t = (unsigned short*)alloc((size_t)8192*2);

  int eb = (N_EDGES+255)/256;
  k_init   <<<NB_ZERO+NB_PACK+NB_PW0+NB_EL0,256,0,stream>>>(h, W0, al0, ar0, W1, al1, ar1,
                                                            deg, Wp, W0t, elr0, xb);
  k_hist   <<<eb,  256,0,stream>>>(dst, deg);
  k_scan   <<<1,  1024,0,stream>>>(deg, offs, cursor);
  k_scatter<<<eb,  256,0,stream>>>(src, dst, cursor, csr_src, csr_eid);

  k_agg0f     <<<N_NODES/4, 256,0,stream>>>(offs, csr_src, xb, elr0, W0t, b0, h1b);
  k_gemm1_mfma<<<(N_NODES+127)/128,256,0,stream>>>(h1b, Wp, featb, elr1);
  k_agg1      <<<N_NODES/4, 256,0,stream>>>(offs, csr_src, csr_eid, featb, elr1, b1, out_final, alpha_out);
}

// Round 12
// 350.470 us; speedup vs baseline: 1.2316x; 1.2316x over previous
//
#include <hip/hip_runtime.h>

#define N_NODES 50000
#define N_EDGES 800000
#define IN_DIM 32
#define HD 256   // H*D
#define H_ 8
#define D_ 32
#define ECAP 64  // edges stashed in LDS per node (recompute tail beyond)
#define NT 17    // 16 W1 col-tiles + 1 Wa1 tile (el/er)

#define NB_ZERO ((N_NODES+255)/256)     // 196
#define NB_PACK ((8*NT*64*8+255)/256)   // 272
#define NB_PW0  32
#define NB_EL0  (N_NODES/16)            // 3125

typedef __attribute__((ext_vector_type(8))) short bf16x8;
typedef __attribute__((ext_vector_type(4))) float f32x4;
typedef __attribute__((ext_vector_type(8))) unsigned short u16x8;

__device__ inline unsigned short f2b(float f){
  union{float f;unsigned int u;}v; v.f=f;
  unsigned int r=(v.u + 0x7FFFu + ((v.u>>16)&1u))>>16;
  return (unsigned short)r;
}
__device__ inline float b2f(unsigned short u){
  union{float f;unsigned int u32;}v; v.u32=((unsigned int)u)<<16; return v.f;
}

// ---------------- fused init: deg-zero | pack W1+Wa1 | pack W0t | el0+xb ----------------

__global__ __launch_bounds__(256) void k_init(const float* __restrict__ h,
    const float* __restrict__ W0, const float* __restrict__ al0, const float* __restrict__ ar0,
    const float* __restrict__ W1, const float* __restrict__ al1, const float* __restrict__ ar1,
    int* __restrict__ deg, unsigned short* __restrict__ Wp, unsigned short* __restrict__ W0t,
    float* __restrict__ elr0, unsigned short* __restrict__ xb){
  int b = blockIdx.x;
  int tid = threadIdx.x;
  if (b < NB_ZERO){
    int i = b*256+tid;
    if (i<N_NODES) deg[i]=0;
    return;
  }
  if (b < NB_ZERO+NB_PACK){
    int t = (b-NB_ZERO)*256+tid;
    if (t < 8*NT*64*8){
      int j=t&7, lane=(t>>3)&63;
      int g=t>>9; int nt=g%NT, ks=g/NT;
      int k = ks*32 + (lane>>4)*8 + j;
      float v;
      if (nt<16){
        v = W1[(size_t)k*HD + nt*16 + (lane&15)];
      } else {
        int jj = lane&15, hh = jj&7;
        const float* av = (jj<8)? al1 : ar1;
        float sacc=0.f;
        #pragma unroll
        for (int d2=0; d2<32; d2++)
          sacc = fmaf(W1[(size_t)k*HD + hh*32 + d2], av[hh*32+d2], sacc);
        v = sacc;
      }
      Wp[t] = f2b(v);
    }
    return;
  }
  if (b < NB_ZERO+NB_PACK+NB_PW0){
    int t = (b-NB_ZERO-NB_PACK)*256+tid;
    if (t < 8192){
      int q = t&7, c = (t>>3)&255, kb = t>>11;
      W0t[t] = f2b(W0[(size_t)(kb*8+q)*HD + c]);
    }
    return;
  }
  // ---- el0 part: elr0 + xb, Wa0 computed inline ----
  int eb = b - (NB_ZERO+NB_PACK+NB_PW0);
  __shared__ float sWa[IN_DIM*16];
  __shared__ float sx[16][IN_DIM+1];
  int nb = eb*16;
  for (int e=tid; e<IN_DIM*16; e+=256){
    int k=e>>4, j=e&15, hh=j&7;
    const float* av = (j<8)? al0 : ar0;
    float sacc=0.f;
    #pragma unroll
    for (int d2=0; d2<32; d2++)
      sacc = fmaf(W0[(size_t)k*HD + hh*32 + d2], av[hh*32+d2], sacc);
    sWa[e]=sacc;
  }
  for (int i=tid; i<16*IN_DIM; i+=256){
    int r=i>>5, c=i&31;
    sx[r][c] = h[(size_t)(nb+r)*IN_DIM + c];
  }
  __syncthreads();
  int node = tid>>4, j = tid&15;
  float s = 0.f;
  #pragma unroll 8
  for (int k=0;k<IN_DIM;k++) s = fmaf(sx[node][k], sWa[k*16+j], s);
  elr0[(size_t)(nb+node)*16 + j] = s;
  for (int i=tid; i<16*IN_DIM; i+=256){
    int r=i>>5, c=i&31;
    xb[(size_t)(nb+r)*IN_DIM + c] = f2b(sx[r][c]);
  }
}

// ---------------- CSR build ----------------

__global__ void k_hist(const int* __restrict__ dst, int* __restrict__ deg){
  int e = blockIdx.x*256+threadIdx.x;
  if (e < N_EDGES) atomicAdd(&deg[dst[e]], 1);
}

__global__ void k_block_sums(const int* __restrict__ deg, int* __restrict__ bsums){
  int i = blockIdx.x*256+threadIdx.x;
  int v = (i<N_NODES)? deg[i]:0;
  #pragma unroll
  for (int o=32;o>=1;o>>=1) v += __shfl_xor(v,o,64);
  __shared__ int ws[4];
  if ((threadIdx.x&63)==0) ws[threadIdx.x>>6]=v;
  __syncthreads();
  if (threadIdx.x==0) bsums[blockIdx.x]=ws[0]+ws[1]+ws[2]+ws[3];
}

__global__ void k_scan_bsums(int* bsums, int nb){
  if (threadIdx.x==0 && blockIdx.x==0){
    int a=0;
    for (int i=0;i<nb;i++){int t=bsums[i]; bsums[i]=a; a+=t;}
  }
}

__device__ inline int wave_incl_scan(int v){
  int lane = threadIdx.x & 63;
  #pragma unroll
  for (int o=1;o<64;o<<=1){
    int t = __shfl_up(v,o,64);
    if (lane>=o) v+=t;
  }
  return v;
}

__global__ void k_scan_chunks(const int* __restrict__ deg, const int* __restrict__ bsums,
                              int* __restrict__ offs, int* __restrict__ cursor){
  int i = blockIdx.x*256+threadIdx.x;
  int v = (i<N_NODES)? deg[i]:0;
  int incl = wave_incl_scan(v);
  __shared__ int ws[4];
  int wid=threadIdx.x>>6, lane=threadIdx.x&63;
  if (lane==63) ws[wid]=incl;
  __syncthreads();
  if (threadIdx.x==0){int a=0; for(int w=0;w<4;w++){int t=ws[w];ws[w]=a;a+=t;}}
  __syncthreads();
  int excl = incl - v + ws[wid] + bsums[blockIdx.x];
  if (i<N_NODES){ offs[i]=excl; cursor[i]=excl; }
  if (i==N_NODES-1) offs[N_NODES]=excl+v;
}

__global__ void k_scatter(const int* __restrict__ src, const int* __restrict__ dst,
                          int* __restrict__ cursor, int* __restrict__ csr_src,
                          int* __restrict__ csr_eid){
  int e = blockIdx.x*256+threadIdx.x;
  if (e<N_EDGES){
    int d = dst[e];
    int pos = atomicAdd(&cursor[d],1);
    csr_src[pos]=src[e];
    csr_eid[pos]=e;
  }
}

// ---------------- FUSED layer-0 (bf16 x gather) ----------------

__global__ __launch_bounds__(256) void k_agg0f(const int* __restrict__ offs, const int* __restrict__ csr_src,
    const unsigned short* __restrict__ xb, const float* __restrict__ elr,
    const unsigned short* __restrict__ W0t, const float* __restrict__ b0,
    unsigned short* __restrict__ h1b){
  __shared__ float s_al[4][ECAP][H_];
  __shared__ int   s_sn[4][ECAP];
  __shared__ float s_m[4][H_], s_is[4][H_];
  __shared__ float s_hg[4][32*9];      // transposed hagg, stride 9 (bank-spread)
  int w = threadIdx.x>>6, lane = threadIdx.x&63;
  int n = blockIdx.x*4 + w;
  int h = lane>>3, sub = lane&7;
  int off = offs[n], deg = offs[n+1]-off;
  float er_n = elr[n*16 + 8 + h];

  // ---- phase A: scores -> LDS, online (m,s) ----
  float m=-1e30f, s=0.f;
  for (int i=sub; i<deg; i+=8){
    int sn = csr_src[off+i];
    float sc = elr[sn*16+h] + er_n;
    sc = sc>0.f? sc : 0.2f*sc;
    if (i<ECAP){ s_al[w][i][h] = sc; if (h==0) s_sn[w][i] = sn; }
    float mn = fmaxf(m,sc);
    s = s*__expf(m-mn) + __expf(sc-mn);
    m = mn;
  }
  #pragma unroll
  for (int o=4;o>=1;o>>=1){
    float m2=__shfl_xor(m,o,64), s2=__shfl_xor(s,o,64);
    float mn=fmaxf(m,m2);
    s = s*__expf(m-mn)+s2*__expf(m2-mn); m=mn;
  }
  float inv_s = (s>0.f)?1.f/s:0.f;
  if (sub==0){ s_m[w][h]=m; s_is[w][h]=inv_s; }
  int dcap = deg<ECAP? deg:ECAP;
  int dcap_pad = (dcap+15)&~15;
  for (int i=sub; i<dcap; i+=8)
    s_al[w][i][h] = __expf(s_al[w][i][h]-m)*inv_s;
  for (int i=dcap+lane; i<dcap_pad; i+=64){   // pad to 16-boundary: zero-alpha dummy edges
    s_sn[w][i]=0;
    *(float4*)&s_al[w][i][0]=make_float4(0,0,0,0);
    *(float4*)&s_al[w][i][4]=make_float4(0,0,0,0);
  }
  __syncthreads();

  // ---- phase B: tail-free 16-edge chunks, bf16 x ----
  int hw = lane>>5, d = lane&31;
  float acc[H_]  = {0,0,0,0,0,0,0,0};
  int i = hw;
  for (; i<dcap_pad; i+=16){
    float xv[8];
    #pragma unroll
    for (int q=0;q<8;q++)
      xv[q] = b2f(xb[(size_t)s_sn[w][i+2*q]*IN_DIM + d]);
    #pragma unroll
    for (int q=0;q<8;q++){
      float4 a0 = *(const float4*)&s_al[w][i+2*q][0];
      float4 a1 = *(const float4*)&s_al[w][i+2*q][4];
      acc[0]=fmaf(a0.x,xv[q],acc[0]); acc[1]=fmaf(a0.y,xv[q],acc[1]);
      acc[2]=fmaf(a0.z,xv[q],acc[2]); acc[3]=fmaf(a0.w,xv[q],acc[3]);
      acc[4]=fmaf(a1.x,xv[q],acc[4]); acc[5]=fmaf(a1.y,xv[q],acc[5]);
      acc[6]=fmaf(a1.z,xv[q],acc[6]); acc[7]=fmaf(a1.w,xv[q],acc[7]);
    }
  }
  for (; i<deg; i+=2){                    // rare tail: deg > ECAP, recompute
    int sn = csr_src[off+i];
    float xv = b2f(xb[(size_t)sn*IN_DIM + d]);
    #pragma unroll
    for (int hh=0;hh<H_;hh++){
      float sc = elr[sn*16+hh] + elr[n*16+8+hh];
      sc = sc>0.f? sc : 0.2f*sc;
      float a = __expf(sc - s_m[w][hh]) * s_is[w][hh];
      acc[hh]=fmaf(a,xv,acc[hh]);
    }
  }
  #pragma unroll
  for (int hh=0;hh<H_;hh++)
    acc[hh] += __shfl_xor(acc[hh],32,64);
  if (hw==0){
    #pragma unroll
    for (int hh=0;hh<H_;hh++) s_hg[w][d*9+hh] = acc[hh];
  }
  __syncthreads();

  // ---- epilogue (column-split): wave w computes cols [w*64, w*64+64) for ALL 4 nodes ----
  int col = w*64 + lane;
  int hcol = col>>5;
  float a0=0.f, a1=0.f, a2=0.f, a3=0.f;
  #pragma unroll
  for (int kb=0;kb<4;kb++){
    u16x8 wv8 = *(const u16x8*)(W0t + ((size_t)(kb*HD + col)<<3));
    #pragma unroll
    for (int q=0;q<8;q++){
      float wv = b2f(wv8[q]);
      int k = kb*8+q;
      a0 = fmaf(s_hg[0][k*9+hcol], wv, a0);
      a1 = fmaf(s_hg[1][k*9+hcol], wv, a1);
      a2 = fmaf(s_hg[2][k*9+hcol], wv, a2);
      a3 = fmaf(s_hg[3][k*9+hcol], wv, a3);
    }
  }
  float bb = b0[col];
  int n0 = blockIdx.x*4;
  h1b[(size_t)(n0+0)*HD+col] = f2b(fmaxf(a0+bb,0.f));
  h1b[(size_t)(n0+1)*HD+col] = f2b(fmaxf(a1+bb,0.f));
  h1b[(size_t)(n0+2)*HD+col] = f2b(fmaxf(a2+bb,0.f));
  h1b[(size_t)(n0+3)*HD+col] = f2b(fmaxf(a3+bb,0.f));
}

// ---------------- feat1 = h1b @ [W1 | Wa1] via MFMA; 32 rows/wave ----------------

__global__ __launch_bounds__(256) void k_gemm1_mfma(const unsigned short* __restrict__ h1b,
    const unsigned short* __restrict__ Wp, unsigned short* __restrict__ featb,
    float* __restrict__ elr1){
  int wv = threadIdx.x>>6, lane = threadIdx.x&63;
  int rb = blockIdx.x*128 + wv*32;
  int ar0 = rb + (lane&15);
  int ar1 = ar0 + 16;
  if (ar0 >= N_NODES) ar0 = N_NODES-1;   // clamp reads; writes guarded below
  if (ar1 >= N_NODES) ar1 = N_NODES-1;
  int kgrp = lane>>4;
  f32x4 acc0[NT], acc1[NT];
  #pragma unroll
  for (int nt=0;nt<NT;nt++){ acc0[nt]=(f32x4){0.f,0.f,0.f,0.f}; acc1[nt]=(f32x4){0.f,0.f,0.f,0.f}; }
  const unsigned short* ap0 = h1b + (size_t)ar0*HD + kgrp*8;
  const unsigned short* ap1 = h1b + (size_t)ar1*HD + kgrp*8;
  #pragma unroll
  for (int ks=0; ks<8; ks++){
    bf16x8 a0 = *(const bf16x8*)(ap0 + ks*32);
    bf16x8 a1 = *(const bf16x8*)(ap1 + ks*32);
    #pragma unroll
    for (int nt=0; nt<NT; nt++){
      bf16x8 b = *(const bf16x8*)(Wp + (((ks*NT+nt)*64+lane)<<3));
      acc0[nt] = __builtin_amdgcn_mfma_f32_16x16x32_bf16(a0, b, acc0[nt], 0, 0, 0);
      acc1[nt] = __builtin_amdgcn_mfma_f32_16x16x32_bf16(a1, b, acc1[nt], 0, 0, 0);
    }
  }
  int col = lane&15;
  int rb0 = rb + (lane>>4)*4;
  int rb1 = rb0 + 16;
  #pragma unroll
  for (int nt=0;nt<16;nt++){
    #pragma unroll
    for (int r=0;r<4;r++){
      int row0 = rb0+r, row1 = rb1+r;
      if (row0<N_NODES) featb[(size_t)row0*HD + nt*16+col] = f2b(acc0[nt][r]);
      if (row1<N_NODES) featb[(size_t)row1*HD + nt*16+col] = f2b(acc1[nt][r]);
    }
  }
  #pragma unroll
  for (int r=0;r<4;r++){
    int row0 = rb0+r, row1 = rb1+r;
    if (row0<N_NODES) elr1[(size_t)row0*16 + col] = acc0[16][r];
    if (row1<N_NODES) elr1[(size_t)row1*16 + col] = acc1[16][r];
  }
}

// ---------------- layer-1 edge softmax + aggregate + head-mean (R9 form) ----------------

__global__ __launch_bounds__(256) void k_agg1(const int* __restrict__ offs, const int* __restrict__ csr_src,
   const int* __restrict__ csr_eid, const unsigned short* __restrict__ featb, const float* __restrict__ elr,
   const float* __restrict__ bias, float* __restrict__ out, float* __restrict__ alpha_out){
  __shared__ float s_al[4][ECAP][H_];
  __shared__ int   s_sn[4][ECAP];
  __shared__ int   s_eid[4][ECAP];
  int w = threadIdx.x>>6, lane = threadIdx.x&63;
  int n = blockIdx.x*4 + w;
  int h = lane>>3, sub = lane&7;
  int off = offs[n], deg = offs[n+1]-off;
  float er_n = elr[n*16 + 8 + h];

  float m=-1e30f, s=0.f;
  for (int i=sub; i<deg; i+=8){
    int p = off+i;
    int sn = csr_src[p];
    float sc = elr[sn*16+h] + er_n;
    sc = sc>0.f? sc : 0.2f*sc;
    if (i<ECAP){
      s_al[w][i][h]=sc;
      if (h==0){ s_sn[w][i]=sn; s_eid[w][i]=csr_eid[p]; }
    }
    float mn = fmaxf(m,sc);
    s = s*__expf(m-mn) + __expf(sc-mn);
    m = mn;
  }
  #pragma unroll
  for (int o=4;o>=1;o>>=1){
    float m2=__shfl_xor(m,o,64), s2=__shfl_xor(s,o,64);
    float mn=fmaxf(m,m2);
    s = s*__expf(m-mn) + s2*__expf(m2-mn);
    m = mn;
  }
  float inv_s = (s>0.f)? 1.f/s : 0.f;
  int dcap = deg<ECAP? deg:ECAP;
  int dcap_pad = (dcap+7)&~7;
  __syncthreads();   // s_eid ready before conversion pass writes alpha
  for (int i=sub; i<dcap; i+=8){
    float a = __expf(s_al[w][i][h]-m)*inv_s;
    s_al[w][i][h] = a;
    alpha_out[(size_t)s_eid[w][i]*H_ + h] = a;
  }
  for (int i=dcap+lane; i<dcap_pad; i+=64){   // pad to 8-boundary: zero-alpha dummy edges
    s_sn[w][i]=0;
    *(float4*)&s_al[w][i][0]=make_float4(0,0,0,0);
    *(float4*)&s_al[w][i][4]=make_float4(0,0,0,0);
  }
  __syncthreads();

  // ---- phase B: full-wave per edge, 8 gathers in flight ----
  int c0 = lane*4;             // cols c0..c0+3 (head h == lane>>3)
  float acc[4] = {0,0,0,0};
  for (int i=0; i<dcap_pad; i+=8){
    float av[8]; ushort4 uu[8];
    #pragma unroll
    for (int q=0;q<8;q++){
      int sn = s_sn[w][i+q];
      av[q] = s_al[w][i+q][h];
      uu[q] = *(const ushort4*)&featb[(size_t)sn*HD + c0];
    }
    #pragma unroll
    for (int q=0;q<8;q++){
      acc[0]=fmaf(av[q],b2f(uu[q].x),acc[0]);
      acc[1]=fmaf(av[q],b2f(uu[q].y),acc[1]);
      acc[2]=fmaf(av[q],b2f(uu[q].z),acc[2]);
      acc[3]=fmaf(av[q],b2f(uu[q].w),acc[3]);
    }
  }
  for (int i=ECAP; i<deg; ++i){           // rare tail: deg > ECAP, full wave per edge
    int p = off+i;
    int sn = csr_src[p];
    float sc = elr[sn*16+h] + er_n;
    sc = sc>0.f? sc : 0.2f*sc;
    float a=__expf(sc-m)*inv_s;
    ushort4 u=*(const ushort4*)&featb[(size_t)sn*HD+c0];
    acc[0]=fmaf(a,b2f(u.x),acc[0]);
    acc[1]=fmaf(a,b2f(u.y),acc[1]);
    acc[2]=fmaf(a,b2f(u.z),acc[2]);
    acc[3]=fmaf(a,b2f(u.w),acc[3]);
    if (sub==0) alpha_out[(size_t)csr_eid[p]*H_+h]=a;
  }

  // bias, then mean over heads (sum lanes with same lane&7)
  #pragma unroll
  for (int q=0;q<4;q++) acc[q] += bias[c0+q];
  #pragma unroll
  for (int o=8;o<64;o<<=1){
    #pragma unroll
    for (int q=0;q<4;q++) acc[q]+=__shfl_xor(acc[q],o,64);
  }
  if (h==0){
    float4 o0 = make_float4(acc[0]*0.125f, acc[1]*0.125f, acc[2]*0.125f, acc[3]*0.125f);
    *(float4*)&out[(size_t)n*D_ + c0] = o0;
  }
}

// ---------------- launcher ----------------

extern "C" void kernel_launch(void* const* d_in, const int* in_sizes, int n_in,
                              void* d_out, int out_size, void* d_ws, size_t ws_size,
                              hipStream_t stream){
  const float* h   = (const float*)d_in[0];
  const int*   src = (const int*)d_in[1];
  const int*   dst = (const int*)d_in[2];
  const float* W0  = (const float*)d_in[3];
  const float* al0 = (const float*)d_in[4];
  const float* ar0 = (const float*)d_in[5];
  const float* b0  = (const float*)d_in[6];
  const float* W1  = (const float*)d_in[7];
  const float* al1 = (const float*)d_in[8];
  const float* ar1 = (const float*)d_in[9];
  const float* b1  = (const float*)d_in[10];
  float* out_final = (float*)d_out;
  float* alpha_out = (float*)d_out + (size_t)N_NODES*D_;

  char* wsp = (char*)d_ws;
  auto alloc=[&](size_t bytes)->char*{ char* p=wsp; wsp += (bytes+255)&~size_t(255); return p; };
  int*   deg     = (int*)alloc((size_t)N_NODES*4);
  int*   offs    = (int*)alloc((size_t)(N_NODES+1)*4);
  int*   cursor  = (int*)alloc((size_t)N_NODES*4);
  int*   bsums   = (int*)alloc(1024);
  int*   csr_src = (int*)alloc((size_t)N_EDGES*4);
  int*   csr_eid = (int*)alloc((size_t)N_EDGES*4);
  unsigned short* featb = (unsigned short*)alloc((size_t)N_NODES*HD*2);
  unsigned short* h1b   = (unsigned short*)alloc((size_t)N_NODES*HD*2);
  unsigned short* xb    = (unsigned short*)alloc((size_t)N_NODES*IN_DIM*2);
  float* elr0    = (float*)alloc((size_t)N_NODES*16*4);
  float* elr1    = (float*)alloc((size_t)N_NODES*16*4);
  unsigned short* Wp  = (unsigned short*)alloc((size_t)8*NT*64*8*2);
  unsigned short* W0t = (unsigned short*)alloc((size_t)8192*2);

  int eb = (N_EDGES+255)/256;
  int nbchunks = (N_NODES+255)/256;
  k_init       <<<NB_ZERO+NB_PACK+NB_PW0+NB_EL0,256,0,stream>>>(h, W0, al0, ar0, W1, al1, ar1,
                                                                deg, Wp, W0t, elr0, xb);
  k_hist       <<<eb,      256,0,stream>>>(dst, deg);
  k_block_sums <<<nbchunks,256,0,stream>>>(deg, bsums);
  k_scan_bsums <<<1,       64, 0,stream>>>(bsums, nbchunks);
  k_scan_chunks<<<nbchunks,256,0,stream>>>(deg, bsums, offs, cursor);
  k_scatter    <<<eb,      256,0,stream>>>(src, dst, cursor, csr_src, csr_eid);

  k_agg0f     <<<N_NODES/4, 256,0,stream>>>(offs, csr_src, xb, elr0, W0t, b0, h1b);
  k_gemm1_mfma<<<(N_NODES+127)/128,256,0,stream>>>(h1b, Wp, featb, elr1);
  k_agg1      <<<N_NODES/4, 256,0,stream>>>(offs, csr_src, csr_eid, featb, elr1, b1, out_final, alpha_out);
}

// Round 13
// 315.817 us; speedup vs baseline: 1.3668x; 1.1097x over previous
//
#include <hip/hip_runtime.h>

#define N_NODES 50000
#define N_EDGES 800000
#define IN_DIM 32
#define HD 256   // H*D
#define H_ 8
#define D_ 32
#define ECAP 64  // edges stashed in LDS per node (recompute tail beyond)
#define NT 17    // 16 W1 col-tiles + 1 Wa1 tile (el/er)

typedef __attribute__((ext_vector_type(8))) short bf16x8;
typedef __attribute__((ext_vector_type(4))) float f32x4;
typedef __attribute__((ext_vector_type(8))) unsigned short u16x8;

__device__ inline unsigned short f2b(float f){
  union{float f;unsigned int u;}v; v.f=f;
  unsigned int r=(v.u + 0x7FFFu + ((v.u>>16)&1u))>>16;
  return (unsigned short)r;
}
__device__ inline float b2f(unsigned short u){
  union{float f;unsigned int u32;}v; v.u32=((unsigned int)u)<<16; return v.f;
}

// ---------------- CSR build ----------------

__global__ void k_hist(const int* __restrict__ dst, int* __restrict__ deg){
  int e = blockIdx.x*256+threadIdx.x;
  if (e < N_EDGES) atomicAdd(&deg[dst[e]], 1);
}

__global__ void k_block_sums(const int* __restrict__ deg, int* __restrict__ bsums){
  int i = blockIdx.x*256+threadIdx.x;
  int v = (i<N_NODES)? deg[i]:0;
  #pragma unroll
  for (int o=32;o>=1;o>>=1) v += __shfl_xor(v,o,64);
  __shared__ int ws[4];
  if ((threadIdx.x&63)==0) ws[threadIdx.x>>6]=v;
  __syncthreads();
  if (threadIdx.x==0) bsums[blockIdx.x]=ws[0]+ws[1]+ws[2]+ws[3];
}

__global__ void k_scan_bsums(int* bsums, int nb){
  if (threadIdx.x==0 && blockIdx.x==0){
    int a=0;
    for (int i=0;i<nb;i++){int t=bsums[i]; bsums[i]=a; a+=t;}
  }
}

__device__ inline int wave_incl_scan(int v){
  int lane = threadIdx.x & 63;
  #pragma unroll
  for (int o=1;o<64;o<<=1){
    int t = __shfl_up(v,o,64);
    if (lane>=o) v+=t;
  }
  return v;
}

__global__ void k_scan_chunks(const int* __restrict__ deg, const int* __restrict__ bsums,
                              int* __restrict__ offs, int* __restrict__ cursor){
  int i = blockIdx.x*256+threadIdx.x;
  int v = (i<N_NODES)? deg[i]:0;
  int incl = wave_incl_scan(v);
  __shared__ int ws[4];
  int wid=threadIdx.x>>6, lane=threadIdx.x&63;
  if (lane==63) ws[wid]=incl;
  __syncthreads();
  if (threadIdx.x==0){int a=0; for(int w=0;w<4;w++){int t=ws[w];ws[w]=a;a+=t;}}
  __syncthreads();
  int excl = incl - v + ws[wid] + bsums[blockIdx.x];
  if (i<N_NODES){ offs[i]=excl; cursor[i]=excl; }
  if (i==N_NODES-1) offs[N_NODES]=excl+v;
}

__global__ void k_scatter(const int* __restrict__ src, const int* __restrict__ dst,
                          int* __restrict__ cursor, int* __restrict__ csr_src,
                          int* __restrict__ csr_eid){
  int e = blockIdx.x*256+threadIdx.x;
  if (e<N_EDGES){
    int d = dst[e];
    int pos = atomicAdd(&cursor[d],1);
    csr_src[pos]=src[e];
    csr_eid[pos]=e;
  }
}

// ---------------- Wa precompute ----------------

template<int K>
__global__ void k_prep(const float* __restrict__ W, const float* __restrict__ al,
                       const float* __restrict__ ar, float* __restrict__ Wa){
  int t = blockIdx.x*256 + threadIdx.x;
  int k = t>>3, hh = t&7;
  if (k < K){
    float sl=0.f, sr=0.f;
    #pragma unroll
    for (int d=0; d<32; d++){
      float w = W[(size_t)k*HD + hh*32 + d];
      sl = fmaf(w, al[hh*32+d], sl);
      sr = fmaf(w, ar[hh*32+d], sr);
    }
    Wa[k*16 + hh]     = sl;
    Wa[k*16 + 8 + hh] = sr;
  }
}

// ---------------- fragment pack: 16 tiles of W1 + 1 tile of Wa1 ----------------

__global__ void k_pack_w(const float* __restrict__ W, const float* __restrict__ Wa1,
                         unsigned short* __restrict__ Wp){
  int t = blockIdx.x*256+threadIdx.x;   // 8*NT*64*8 = 69632 total
  if (t >= 8*NT*64*8) return;
  int j=t&7, lane=(t>>3)&63;
  int g=t>>9; int nt=g%NT, ks=g/NT;
  int k = ks*32 + (lane>>4)*8 + j;
  float v;
  if (nt<16) v = W[(size_t)k*HD + nt*16 + (lane&15)];
  else       v = Wa1[k*16 + (lane&15)];
  Wp[t] = f2b(v);
}

// ---------------- W0 pack (bf16, k-major per col) ----------------

__global__ void k_pack_w0(const float* __restrict__ W0, unsigned short* __restrict__ W0t){
  int t = blockIdx.x*256+threadIdx.x;   // 8192 total
  if (t < 8192){
    int q = t&7, c = (t>>3)&255, kb = t>>11;
    W0t[t] = f2b(W0[(size_t)(kb*8+q)*HD + c]);
  }
}

// ---------------- el/er (layer 0, f32 input K=32) ----------------

template<int K>
__global__ __launch_bounds__(256) void k_el(const float* __restrict__ x, const float* __restrict__ Wa,
                                            float* __restrict__ elr){
  __shared__ float sWa[K*16];
  __shared__ float sx[16][K+1];
  int tid = threadIdx.x;
  int nb = blockIdx.x*16;
  for (int i = tid; i < K*16; i += 256) sWa[i] = Wa[i];
  for (int i = tid; i < 16*K; i += 256){
    int r = i / K, c = i % K;
    sx[r][c] = x[(size_t)(nb+r)*K + c];
  }
  __syncthreads();
  int node = tid>>4, j = tid&15;
  float s = 0.f;
  #pragma unroll 8
  for (int k=0;k<K;k++) s = fmaf(sx[node][k], sWa[k*16+j], s);
  elr[(size_t)(nb+node)*16 + j] = s;
}

// ---------------- FUSED layer-0 ----------------

__global__ __launch_bounds__(256) void k_agg0f(const int* __restrict__ offs, const int* __restrict__ csr_src,
    const float* __restrict__ x, const float* __restrict__ elr,
    const unsigned short* __restrict__ W0t, const float* __restrict__ b0,
    unsigned short* __restrict__ h1b){
  __shared__ float s_al[4][ECAP][H_];
  __shared__ int   s_sn[4][ECAP];
  __shared__ float s_m[4][H_], s_is[4][H_];
  __shared__ float s_hg[4][32*9];      // transposed hagg, stride 9 (bank-spread)
  int w = threadIdx.x>>6, lane = threadIdx.x&63;
  int n = blockIdx.x*4 + w;
  int h = lane>>3, sub = lane&7;
  int off = offs[n], deg = offs[n+1]-off;
  float er_n = elr[n*16 + 8 + h];

  // ---- phase A: scores -> LDS, online (m,s) ----
  float m=-1e30f, s=0.f;
  for (int i=sub; i<deg; i+=8){
    int sn = csr_src[off+i];
    float sc = elr[sn*16+h] + er_n;
    sc = sc>0.f? sc : 0.2f*sc;
    if (i<ECAP){ s_al[w][i][h] = sc; if (h==0) s_sn[w][i] = sn; }
    float mn = fmaxf(m,sc);
    s = s*__expf(m-mn) + __expf(sc-mn);
    m = mn;
  }
  #pragma unroll
  for (int o=4;o>=1;o>>=1){
    float m2=__shfl_xor(m,o,64), s2=__shfl_xor(s,o,64);
    float mn=fmaxf(m,m2);
    s = s*__expf(m-mn)+s2*__expf(m2-mn); m=mn;
  }
  float inv_s = (s>0.f)?1.f/s:0.f;
  if (sub==0){ s_m[w][h]=m; s_is[w][h]=inv_s; }
  int dcap = deg<ECAP? deg:ECAP;
  int dcap_pad = (dcap+15)&~15;
  for (int i=sub; i<dcap; i+=8)
    s_al[w][i][h] = __expf(s_al[w][i][h]-m)*inv_s;
  for (int i=dcap+lane; i<dcap_pad; i+=64){   // pad to 16-boundary: zero-alpha dummy edges
    s_sn[w][i]=0;
    *(float4*)&s_al[w][i][0]=make_float4(0,0,0,0);
    *(float4*)&s_al[w][i][4]=make_float4(0,0,0,0);
  }
  __syncthreads();

  // ---- phase B: tail-free 16-edge chunks, 8 gathers in flight per half-wave ----
  int hw = lane>>5, d = lane&31;
  float acc[H_]  = {0,0,0,0,0,0,0,0};
  int i = hw;
  for (; i<dcap_pad; i+=16){
    float xv[8];
    #pragma unroll
    for (int q=0;q<8;q++)
      xv[q] = x[(size_t)s_sn[w][i+2*q]*IN_DIM + d];
    #pragma unroll
    for (int q=0;q<8;q++){
      float4 a0 = *(const float4*)&s_al[w][i+2*q][0];
      float4 a1 = *(const float4*)&s_al[w][i+2*q][4];
      acc[0]=fmaf(a0.x,xv[q],acc[0]); acc[1]=fmaf(a0.y,xv[q],acc[1]);
      acc[2]=fmaf(a0.z,xv[q],acc[2]); acc[3]=fmaf(a0.w,xv[q],acc[3]);
      acc[4]=fmaf(a1.x,xv[q],acc[4]); acc[5]=fmaf(a1.y,xv[q],acc[5]);
      acc[6]=fmaf(a1.z,xv[q],acc[6]); acc[7]=fmaf(a1.w,xv[q],acc[7]);
    }
  }
  for (; i<deg; i+=2){                    // rare tail: deg > ECAP, recompute
    int sn = csr_src[off+i];
    float xv = x[(size_t)sn*IN_DIM + d];
    #pragma unroll
    for (int hh=0;hh<H_;hh++){
      float sc = elr[sn*16+hh] + elr[n*16+8+hh];
      sc = sc>0.f? sc : 0.2f*sc;
      float a = __expf(sc - s_m[w][hh]) * s_is[w][hh];
      acc[hh]=fmaf(a,xv,acc[hh]);
    }
  }
  #pragma unroll
  for (int hh=0;hh<H_;hh++)
    acc[hh] += __shfl_xor(acc[hh],32,64);
  if (hw==0){
    #pragma unroll
    for (int hh=0;hh<H_;hh++) s_hg[w][d*9+hh] = acc[hh];
  }
  __syncthreads();

  // ---- epilogue (column-split): wave w computes cols [w*64, w*64+64) for ALL 4 nodes ----
  int col = w*64 + lane;
  int hcol = col>>5;
  float a0=0.f, a1=0.f, a2=0.f, a3=0.f;
  #pragma unroll
  for (int kb=0;kb<4;kb++){
    u16x8 wv8 = *(const u16x8*)(W0t + ((size_t)(kb*HD + col)<<3));
    #pragma unroll
    for (int q=0;q<8;q++){
      float wv = b2f(wv8[q]);
      int k = kb*8+q;
      a0 = fmaf(s_hg[0][k*9+hcol], wv, a0);
      a1 = fmaf(s_hg[1][k*9+hcol], wv, a1);
      a2 = fmaf(s_hg[2][k*9+hcol], wv, a2);
      a3 = fmaf(s_hg[3][k*9+hcol], wv, a3);
    }
  }
  float bb = b0[col];
  int n0 = blockIdx.x*4;
  h1b[(size_t)(n0+0)*HD+col] = f2b(fmaxf(a0+bb,0.f));
  h1b[(size_t)(n0+1)*HD+col] = f2b(fmaxf(a1+bb,0.f));
  h1b[(size_t)(n0+2)*HD+col] = f2b(fmaxf(a2+bb,0.f));
  h1b[(size_t)(n0+3)*HD+col] = f2b(fmaxf(a3+bb,0.f));
}

// ---------------- feat1 = h1b @ [W1 | Wa1] via MFMA; 32 rows/wave ----------------

__global__ __launch_bounds__(256) void k_gemm1_mfma(const unsigned short* __restrict__ h1b,
    const unsigned short* __restrict__ Wp, unsigned short* __restrict__ featb,
    float* __restrict__ elr1){
  int wv = threadIdx.x>>6, lane = threadIdx.x&63;
  int rb = blockIdx.x*128 + wv*32;
  int ar0 = rb + (lane&15);
  int ar1 = ar0 + 16;
  if (ar0 >= N_NODES) ar0 = N_NODES-1;   // clamp reads; writes guarded below
  if (ar1 >= N_NODES) ar1 = N_NODES-1;
  int kgrp = lane>>4;
  f32x4 acc0[NT], acc1[NT];
  #pragma unroll
  for (int nt=0;nt<NT;nt++){ acc0[nt]=(f32x4){0.f,0.f,0.f,0.f}; acc1[nt]=(f32x4){0.f,0.f,0.f,0.f}; }
  const unsigned short* ap0 = h1b + (size_t)ar0*HD + kgrp*8;
  const unsigned short* ap1 = h1b + (size_t)ar1*HD + kgrp*8;
  #pragma unroll
  for (int ks=0; ks<8; ks++){
    bf16x8 a0 = *(const bf16x8*)(ap0 + ks*32);
    bf16x8 a1 = *(const bf16x8*)(ap1 + ks*32);
    #pragma unroll
    for (int nt=0; nt<NT; nt++){
      bf16x8 b = *(const bf16x8*)(Wp + (((ks*NT+nt)*64+lane)<<3));
      acc0[nt] = __builtin_amdgcn_mfma_f32_16x16x32_bf16(a0, b, acc0[nt], 0, 0, 0);
      acc1[nt] = __builtin_amdgcn_mfma_f32_16x16x32_bf16(a1, b, acc1[nt], 0, 0, 0);
    }
  }
  int col = lane&15;
  int rb0 = rb + (lane>>4)*4;
  int rb1 = rb0 + 16;
  #pragma unroll
  for (int nt=0;nt<16;nt++){
    #pragma unroll
    for (int r=0;r<4;r++){
      int row0 = rb0+r, row1 = rb1+r;
      if (row0<N_NODES) featb[(size_t)row0*HD + nt*16+col] = f2b(acc0[nt][r]);
      if (row1<N_NODES) featb[(size_t)row1*HD + nt*16+col] = f2b(acc1[nt][r]);
    }
  }
  #pragma unroll
  for (int r=0;r<4;r++){
    int row0 = rb0+r, row1 = rb1+r;
    if (row0<N_NODES) elr1[(size_t)row0*16 + col] = acc0[16][r];
    if (row1<N_NODES) elr1[(size_t)row1*16 + col] = acc1[16][r];
  }
}

// ---------------- layer-1 edge softmax + aggregate + head-mean ----------------
// phase A: (h=lane>>3, sub=lane&7). phase B: FULL WAVE per edge, lane -> cols lane*4..+3, head lane>>3.

__global__ __launch_bounds__(256) void k_agg1(const int* __restrict__ offs, const int* __restrict__ csr_src,
   const int* __restrict__ csr_eid, const unsigned short* __restrict__ featb, const float* __restrict__ elr,
   const float* __restrict__ bias, float* __restrict__ out, float* __restrict__ alpha_out){
  __shared__ float s_al[4][ECAP][H_];
  __shared__ int   s_sn[4][ECAP];
  __shared__ int   s_eid[4][ECAP];
  int w = threadIdx.x>>6, lane = threadIdx.x&63;
  int n = blockIdx.x*4 + w;
  int h = lane>>3, sub = lane&7;
  int off = offs[n], deg = offs[n+1]-off;
  float er_n = elr[n*16 + 8 + h];

  float m=-1e30f, s=0.f;
  for (int i=sub; i<deg; i+=8){
    int p = off+i;
    int sn = csr_src[p];
    float sc = elr[sn*16+h] + er_n;
    sc = sc>0.f? sc : 0.2f*sc;
    if (i<ECAP){
      s_al[w][i][h]=sc;
      if (h==0){ s_sn[w][i]=sn; s_eid[w][i]=csr_eid[p]; }
    }
    float mn = fmaxf(m,sc);
    s = s*__expf(m-mn) + __expf(sc-mn);
    m = mn;
  }
  #pragma unroll
  for (int o=4;o>=1;o>>=1){
    float m2=__shfl_xor(m,o,64), s2=__shfl_xor(s,o,64);
    float mn=fmaxf(m,m2);
    s = s*__expf(m-mn) + s2*__expf(m2-mn);
    m = mn;
  }
  float inv_s = (s>0.f)? 1.f/s : 0.f;
  int dcap = deg<ECAP? deg:ECAP;
  int dcap_pad = (dcap+7)&~7;
  __syncthreads();   // s_eid ready before conversion pass writes alpha
  for (int i=sub; i<dcap; i+=8){
    float a = __expf(s_al[w][i][h]-m)*inv_s;
    s_al[w][i][h] = a;
    alpha_out[(size_t)s_eid[w][i]*H_ + h] = a;
  }
  for (int i=dcap+lane; i<dcap_pad; i+=64){   // pad to 8-boundary: zero-alpha dummy edges
    s_sn[w][i]=0;
    *(float4*)&s_al[w][i][0]=make_float4(0,0,0,0);
    *(float4*)&s_al[w][i][4]=make_float4(0,0,0,0);
  }
  __syncthreads();

  // ---- phase B: full-wave per edge, 8 gathers in flight ----
  int c0 = lane*4;             // cols c0..c0+3 (head h == lane>>3)
  float acc[4] = {0,0,0,0};
  for (int i=0; i<dcap_pad; i+=8){
    float av[8]; ushort4 uu[8];
    #pragma unroll
    for (int q=0;q<8;q++){
      int sn = s_sn[w][i+q];
      av[q] = s_al[w][i+q][h];
      uu[q] = *(const ushort4*)&featb[(size_t)sn*HD + c0];
    }
    #pragma unroll
    for (int q=0;q<8;q++){
      acc[0]=fmaf(av[q],b2f(uu[q].x),acc[0]);
      acc[1]=fmaf(av[q],b2f(uu[q].y),acc[1]);
      acc[2]=fmaf(av[q],b2f(uu[q].z),acc[2]);
      acc[3]=fmaf(av[q],b2f(uu[q].w),acc[3]);
    }
  }
  for (int i=ECAP; i<deg; ++i){           // rare tail: deg > ECAP, full wave per edge
    int p = off+i;
    int sn = csr_src[p];
    float sc = elr[sn*16+h] + er_n;
    sc = sc>0.f? sc : 0.2f*sc;
    float a=__expf(sc-m)*inv_s;
    ushort4 u=*(const ushort4*)&featb[(size_t)sn*HD+c0];
    acc[0]=fmaf(a,b2f(u.x),acc[0]);
    acc[1]=fmaf(a,b2f(u.y),acc[1]);
    acc[2]=fmaf(a,b2f(u.z),acc[2]);
    acc[3]=fmaf(a,b2f(u.w),acc[3]);
    if (sub==0) alpha_out[(size_t)csr_eid[p]*H_+h]=a;
  }

  // bias, then mean over heads (sum lanes with same lane&7)
  #pragma unroll
  for (int q=0;q<4;q++) acc[q] += bias[c0+q];
  #pragma unroll
  for (int o=8;o<64;o<<=1){
    #pragma unroll
    for (int q=0;q<4;q++) acc[q]+=__shfl_xor(acc[q],o,64);
  }
  if (h==0){
    float4 o0 = make_float4(acc[0]*0.125f, acc[1]*0.125f, acc[2]*0.125f, acc[3]*0.125f);
    *(float4*)&out[(size_t)n*D_ + c0] = o0;
  }
}

// ---------------- launcher ----------------

extern "C" void kernel_launch(void* const* d_in, const int* in_sizes, int n_in,
                              void* d_out, int out_size, void* d_ws, size_t ws_size,
                              hipStream_t stream){
  const float* h   = (const float*)d_in[0];
  const int*   src = (const int*)d_in[1];
  const int*   dst = (const int*)d_in[2];
  const float* W0  = (const float*)d_in[3];
  const float* al0 = (const float*)d_in[4];
  const float* ar0 = (const float*)d_in[5];
  const float* b0  = (const float*)d_in[6];
  const float* W1  = (const float*)d_in[7];
  const float* al1 = (const float*)d_in[8];
  const float* ar1 = (const float*)d_in[9];
  const float* b1  = (const float*)d_in[10];
  float* out_final = (float*)d_out;
  float* alpha_out = (float*)d_out + (size_t)N_NODES*D_;

  char* wsp = (char*)d_ws;
  auto alloc=[&](size_t bytes)->char*{ char* p=wsp; wsp += (bytes+255)&~size_t(255); return p; };
  int*   deg     = (int*)alloc((size_t)N_NODES*4);
  int*   offs    = (int*)alloc((size_t)(N_NODES+1)*4);
  int*   cursor  = (int*)alloc((size_t)N_NODES*4);
  int*   bsums   = (int*)alloc(1024);
  int*   csr_src = (int*)alloc((size_t)N_EDGES*4);
  int*   csr_eid = (int*)alloc((size_t)N_EDGES*4);
  unsigned short* featb = (unsigned short*)alloc((size_t)N_NODES*HD*2);
  unsigned short* h1b   = (unsigned short*)alloc((size_t)N_NODES*HD*2);
  float* elr0    = (float*)alloc((size_t)N_NODES*16*4);
  float* elr1    = (float*)alloc((size_t)N_NODES*16*4);
  float* Wa0     = (float*)alloc((size_t)IN_DIM*16*4);
  float* Wa1     = (float*)alloc((size_t)HD*16*4);
  unsigned short* Wp  = (unsigned short*)alloc((size_t)8*NT*64*8*2);
  unsigned short* W0t = (unsigned short*)alloc((size_t)8192*2);

  hipMemsetAsync(deg, 0, (size_t)N_NODES*4, stream);
  int eb = (N_EDGES+255)/256;
  int nbchunks = (N_NODES+255)/256;
  k_hist       <<<eb,      256,0,stream>>>(dst, deg);
  k_block_sums <<<nbchunks,256,0,stream>>>(deg, bsums);
  k_scan_bsums <<<1,       64, 0,stream>>>(bsums, nbchunks);
  k_scan_chunks<<<nbchunks,256,0,stream>>>(deg, bsums, offs, cursor);
  k_scatter    <<<eb,      256,0,stream>>>(src, dst, cursor, csr_src, csr_eid);

  k_prep<IN_DIM><<<1,256,0,stream>>>(W0, al0, ar0, Wa0);
  k_prep<HD>    <<<8,256,0,stream>>>(W1, al1, ar1, Wa1);
  k_pack_w      <<<(8*NT*64*8+255)/256,256,0,stream>>>(W1, Wa1, Wp);
  k_pack_w0     <<<32,256,0,stream>>>(W0, W0t);

  k_el<IN_DIM><<<N_NODES/16,256,0,stream>>>(h, Wa0, elr0);
  k_agg0f     <<<N_NODES/4, 256,0,stream>>>(offs, csr_src, h, elr0, W0t, b0, h1b);
  k_gemm1_mfma<<<(N_NODES+127)/128,256,0,stream>>>(h1b, Wp, featb, elr1);
  k_agg1      <<<N_NODES/4, 256,0,stream>>>(offs, csr_src, csr_eid, featb, elr1, b1, out_final, alpha_out);
}